// Round 1
// baseline (323.240 us; speedup 1.0000x reference)
//
#include <hip/hip_runtime.h>
#include <math.h>

#define D_DIM 2048
#define T_DIM 128
#define TT 8   // t-values per block

// LDS bank swizzle: bank-group bits of the row become (e1^e6, e0^e2^e5).
// Chosen so every pass's wave-level access pattern is <=2-way (free).
__device__ __forceinline__ int esw(int e) {
    return e ^ ((((e >> 2) ^ (e >> 5)) & 1) | (((e >> 6) & 1) << 1));
}

// radix-2 butterfly over register-index bit MM (fully unrolled, constant idx)
#define BFLY(MM)                                              \
    _Pragma("unroll")                                         \
    for (int i_ = 0; i_ < 64; ++i_) {                         \
        if ((i_ & (MM)) == 0) {                               \
            float a_ = v[i_], b_ = v[i_ | (MM)];              \
            v[i_] = a_ + b_;                                  \
            v[i_ | (MM)] = a_ - b_;                           \
        }                                                     \
    }

__global__ __launch_bounds__(256, 2)
void fwht_apply_kernel(const float* __restrict__ z,
                       const float* __restrict__ d1,
                       const float* __restrict__ d2,
                       const float* __restrict__ d3,
                       const float* __restrict__ bvec,
                       float* __restrict__ out) {
    __shared__ float lds[D_DIM * TT];           // 64 KiB
    const int tid = threadIdx.x;
    const int r   = tid >> 3;                   // 5-bit "rest" coordinate
    const int tt  = tid & 7;                    // t within tile
    const int bid = blockIdx.x;
    const int km  = bid >> 4;                   // which (k,m) slab (128 total)
    const int t0  = (bid & 15) << 3;            // t-tile base (16 tiles)
    const float s = 0.022097086912079608f;      // 1/sqrt(2048), one per H

    const float* zb = z + ((size_t)km * D_DIM) * T_DIM + t0 + tt;
    float v[64];

    // ---- P1: e = (j<<5) | r.  Load * (d1*s); F1 stages on e-bits 5..10 ----
    #pragma unroll
    for (int j = 0; j < 64; ++j) {
        const int e = (j << 5) | r;
        v[j] = zb[(size_t)e * T_DIM] * (d1[e] * s);
    }
    BFLY(1) BFLY(2) BFLY(4) BFLY(8) BFLY(16) BFLY(32)

    #pragma unroll
    for (int j = 0; j < 64; ++j) {
        const int e = (j << 5) | r;
        lds[esw(e) * TT + tt] = v[j];
    }
    __syncthreads();

    // ---- P2: e = (j&31) | ((j>>5)<<10) | (r<<5) ----
    #pragma unroll
    for (int j = 0; j < 64; ++j) {
        const int e = (j & 31) | ((j >> 5) << 10) | (r << 5);
        v[j] = lds[esw(e) * TT + tt];
    }
    __syncthreads();
    BFLY(1) BFLY(2) BFLY(4) BFLY(8) BFLY(16)        // F1 e-bits 0..4 (F1 done)
    {   // * d2 * s : per-thread e is two contiguous runs of 32 -> float4
        const float4* q0 = (const float4*)(d2 + (r << 5));
        const float4* q1 = (const float4*)(d2 + 1024 + (r << 5));
        #pragma unroll
        for (int q = 0; q < 8; ++q) {
            float4 a = q0[q];
            v[4*q+0] *= a.x * s; v[4*q+1] *= a.y * s;
            v[4*q+2] *= a.z * s; v[4*q+3] *= a.w * s;
            float4 c = q1[q];
            v[32+4*q+0] *= c.x * s; v[32+4*q+1] *= c.y * s;
            v[32+4*q+2] *= c.z * s; v[32+4*q+3] *= c.w * s;
        }
    }
    BFLY(1) BFLY(2) BFLY(4) BFLY(8) BFLY(16) BFLY(32)  // F2 e-bits 0..4,10

    #pragma unroll
    for (int j = 0; j < 64; ++j) {
        const int e = (j & 31) | ((j >> 5) << 10) | (r << 5);
        lds[esw(e) * TT + tt] = v[j];
    }
    __syncthreads();

    // ---- P3: e = ((j&31)<<5) | (j>>5) | eRest ----
    const int eRest = ((r & 15) << 1) | ((r >> 4) << 10);
    #pragma unroll
    for (int j = 0; j < 64; ++j) {
        const int e = ((j & 31) << 5) | (j >> 5) | eRest;
        v[j] = lds[esw(e) * TT + tt];
    }
    __syncthreads();
    BFLY(1) BFLY(2) BFLY(4) BFLY(8) BFLY(16)        // F2 e-bits 5..9 (F2 done)
    {   // * d3 * s : (j, j+32) sit at (e, e+1) -> float2
        #pragma unroll
        for (int j = 0; j < 32; ++j) {
            float2 a = *(const float2*)(d3 + ((j << 5) | eRest));
            v[j]      *= a.x * s;
            v[j + 32] *= a.y * s;
        }
    }
    BFLY(1) BFLY(2) BFLY(4) BFLY(8) BFLY(16) BFLY(32)  // F3 e-bits 5..9,0

    #pragma unroll
    for (int j = 0; j < 64; ++j) {
        const int e = ((j & 31) << 5) | (j >> 5) | eRest;
        lds[esw(e) * TT + tt] = v[j];
    }
    __syncthreads();

    // ---- P4: same e-map as P2.  F3 on e-bits 1..4,10 (j-bit 0 = b0 done) ----
    #pragma unroll
    for (int j = 0; j < 64; ++j) {
        const int e = (j & 31) | ((j >> 5) << 10) | (r << 5);
        v[j] = lds[esw(e) * TT + tt];
    }
    BFLY(2) BFLY(4) BFLY(8) BFLY(16) BFLY(32)          // F3 done

    float* ob = out + ((size_t)km * D_DIM) * T_DIM + t0 + tt;
    {   // + b, store.  b is two contiguous runs of 32 -> float4
        const float4* q0 = (const float4*)(bvec + (r << 5));
        const float4* q1 = (const float4*)(bvec + 1024 + (r << 5));
        #pragma unroll
        for (int q = 0; q < 8; ++q) {
            float4 a = q0[q];
            const int e0 = (r << 5) + 4*q;
            ob[(size_t)(e0+0) * T_DIM] = v[4*q+0] + a.x;
            ob[(size_t)(e0+1) * T_DIM] = v[4*q+1] + a.y;
            ob[(size_t)(e0+2) * T_DIM] = v[4*q+2] + a.z;
            ob[(size_t)(e0+3) * T_DIM] = v[4*q+3] + a.w;
            float4 c = q1[q];
            const int e1 = 1024 + (r << 5) + 4*q;
            ob[(size_t)(e1+0) * T_DIM] = v[32+4*q+0] + c.x;
            ob[(size_t)(e1+1) * T_DIM] = v[32+4*q+1] + c.y;
            ob[(size_t)(e1+2) * T_DIM] = v[32+4*q+2] + c.z;
            ob[(size_t)(e1+3) * T_DIM] = v[32+4*q+3] + c.w;
        }
    }
}

__global__ void sldj_kernel(const float* __restrict__ d1,
                            const float* __restrict__ d2,
                            const float* __restrict__ d3,
                            const float* __restrict__ sldj_in,
                            float* __restrict__ out) {
    __shared__ float red[256];
    const int tid = threadIdx.x;
    float acc = 0.0f;
    for (int i = tid; i < D_DIM; i += 256) {
        acc += logf(fabsf(d1[i])) + logf(fabsf(d2[i])) + logf(fabsf(d3[i]));
    }
    red[tid] = acc;
    __syncthreads();
    #pragma unroll
    for (int sft = 128; sft > 0; sft >>= 1) {
        if (tid < sft) red[tid] += red[tid + sft];
        __syncthreads();
    }
    const float tot = red[0];
    if (tid < 128) out[tid] = sldj_in[tid] + tot;
}

extern "C" void kernel_launch(void* const* d_in, const int* in_sizes, int n_in,
                              void* d_out, int out_size, void* d_ws, size_t ws_size,
                              hipStream_t stream) {
    const float* z    = (const float*)d_in[0];
    const float* d1   = (const float*)d_in[1];
    const float* d2   = (const float*)d_in[2];
    const float* d3   = (const float*)d_in[3];
    const float* bvec = (const float*)d_in[4];
    const float* sldj = (const float*)d_in[5];
    float* out = (float*)d_out;

    // K*M = 128 slabs, 16 t-tiles each -> 2048 blocks
    fwht_apply_kernel<<<2048, 256, 0, stream>>>(z, d1, d2, d3, bvec, out);
    sldj_kernel<<<1, 256, 0, stream>>>(d1, d2, d3, sldj,
                                       out + (size_t)4 * 32 * 2048 * 128);
}